// Round 1
// baseline (1342.553 us; speedup 1.0000x reference)
//
#include <hip/hip_runtime.h>
#include <hip/hip_bf16.h>

#define D_IN 32
#define D_MODEL 128
#define BATCH 512
#define TT 512
#define GB 16   // batch rows per block

typedef __attribute__((ext_vector_type(8))) short bf16x8;
typedef __attribute__((ext_vector_type(4))) float f32x4;

__device__ inline short bf16_of(float f) {
    union { float f; unsigned u; } v; v.f = f;
    unsigned r = v.u + 0x7FFFu + ((v.u >> 16) & 1u);
    return (short)(r >> 16);
}

__device__ inline bf16x8 load8_bf16(const float* __restrict__ p) {
    bf16x8 r;
#pragma unroll
    for (int e = 0; e < 8; ++e) r[e] = bf16_of(p[e]);
    return r;
}

__device__ inline float sigmoidf_fast(float x) {
    return 1.0f / (1.0f + __expf(-x));
}
__device__ inline float tanhf_fast(float x) {
    // 1 - 2/(e^{2x}+1); correct saturation at +/-inf
    return 1.0f - 2.0f / (__expf(2.0f * x) + 1.0f);
}

__launch_bounds__(256, 1)
__global__ void rnn_imputer(const float* __restrict__ x,
                            const float* __restrict__ W_ih,
                            const float* __restrict__ W_hh,
                            const float* __restrict__ b_ih,
                            const float* __restrict__ b_hh,
                            const float* __restrict__ W_out,
                            const float* __restrict__ b_out,
                            const int*   __restrict__ mask,
                            float* __restrict__ out) {
    // LDS
    __shared__ __align__(16) short xt_h[GB][200];   // bf16: [0,64)=x_t(x_p|maskf), [64,192)=h, pad to 200
    __shared__ float gates[GB][516];                // r:0..127 z:128..255 xn:256..383 hn:384..511 (+pad)
    __shared__ float h_f[GB][D_MODEL];              // fp32 hidden state
    __shared__ float xh[GB][D_IN];                  // fp32 x_hat (prediction)

    const int tid  = threadIdx.x;
    const int wv   = tid >> 6;       // wave 0..3
    const int lane = tid & 63;
    const int q    = lane >> 4;      // quad 0..3
    const int c    = lane & 15;
    const int bb   = blockIdx.x * GB;

    // ---- B fragments (weights, bf16), stationary in registers ----
    // wave wv owns gate-cols i in [wv*32, wv*32+32) for each of r,z,xn,hn
    bf16x8 Br[2][6], Bz[2][6], Bxn[2][2], Bhn[2][4], Bo[4];
#pragma unroll
    for (int nt = 0; nt < 2; ++nt) {
        const int i = wv * 32 + nt * 16 + c;   // 0..127
#pragma unroll
        for (int kt = 0; kt < 6; ++kt) {
            const int k = kt * 32 + q * 8;     // fused K: [0,64)=W_ih, [64,192)=W_hh
            const float* sr = (k < 64) ? (W_ih + (size_t)i * 64 + k)
                                       : (W_hh + (size_t)i * 128 + (k - 64));
            Br[nt][kt] = load8_bf16(sr);
            const float* sz = (k < 64) ? (W_ih + (size_t)(128 + i) * 64 + k)
                                       : (W_hh + (size_t)(128 + i) * 128 + (k - 64));
            Bz[nt][kt] = load8_bf16(sz);
        }
#pragma unroll
        for (int kt = 0; kt < 2; ++kt)
            Bxn[nt][kt] = load8_bf16(W_ih + (size_t)(256 + i) * 64 + kt * 32 + q * 8);
#pragma unroll
        for (int kt = 0; kt < 4; ++kt)
            Bhn[nt][kt] = load8_bf16(W_hh + (size_t)(256 + i) * 128 + kt * 32 + q * 8);
    }
    float bo = 0.0f;
    if (wv < 2) {
        const int col = wv * 16 + c;           // 0..31
#pragma unroll
        for (int kt = 0; kt < 4; ++kt)
            Bo[kt] = load8_bf16(W_out + (size_t)col * 128 + kt * 32 + q * 8);
        bo = b_out[col];
    }

    // biases for elementwise phase: thread handles hidden unit ei for 8 batches
    const int ei = tid & 127;
    const int bg = tid >> 7;
    const float bR  = b_ih[ei]       + b_hh[ei];
    const float bZ  = b_ih[128 + ei] + b_hh[128 + ei];
    const float bXN = b_ih[256 + ei];
    const float bHN = b_hh[256 + ei];

    // ---- init: h=0, x_hat = b_out, out[:,0,:] = b_out ----
    for (int e = tid; e < GB * D_MODEL; e += 256) {
        const int b = e >> 7, i = e & 127;
        h_f[b][i] = 0.0f;
        xt_h[b][64 + i] = (short)0;
    }
    for (int e = tid; e < GB * D_IN; e += 256) {
        const int b = e >> 5, i = e & 31;
        const float v = b_out[i];
        xh[b][i] = v;
        out[((size_t)(bb + b) * TT) * D_IN + i] = v;
    }
    __syncthreads();

    // prefetch x/mask for t=0 (each thread covers two (b,i) pairs)
    const int b0 = tid >> 5, i0 = tid & 31;
    const int b1 = (tid + 256) >> 5, i1 = tid & 31;
    float xv0, xv1; int mk0, mk1;
    {
        const size_t o0 = ((size_t)(bb + b0) * TT) * D_IN + i0;
        const size_t o1 = ((size_t)(bb + b1) * TT) * D_IN + i1;
        xv0 = x[o0]; mk0 = mask[o0];
        xv1 = x[o1]; mk1 = mask[o1];
    }

    for (int t = 0; t < TT - 1; ++t) {
        // (a) stage x_t = [where(mask, x, x_hat) | mask_f] as bf16
        {
            const float xp0 = mk0 ? xv0 : xh[b0][i0];
            const float xp1 = mk1 ? xv1 : xh[b1][i1];
            xt_h[b0][i0]      = bf16_of(xp0);
            xt_h[b0][32 + i0] = mk0 ? (short)0x3F80 : (short)0;
            xt_h[b1][i1]      = bf16_of(xp1);
            xt_h[b1][32 + i1] = mk1 ? (short)0x3F80 : (short)0;
            // prefetch next step (t+1 <= TT-1 is always in-bounds)
            const size_t o0 = ((size_t)(bb + b0) * TT + (t + 1)) * D_IN + i0;
            const size_t o1 = ((size_t)(bb + b1) * TT + (t + 1)) * D_IN + i1;
            xv0 = x[o0]; mk0 = mask[o0];
            xv1 = x[o1]; mk1 = mask[o1];
        }
        __syncthreads();

        // (c) gate GEMMs via MFMA, weights stationary
        bf16x8 A[6];
#pragma unroll
        for (int kt = 0; kt < 6; ++kt)
            A[kt] = *(const bf16x8*)&xt_h[c][kt * 32 + q * 8];

        f32x4 accR[2], accZ[2], accXN[2], accHN[2];
#pragma unroll
        for (int nt = 0; nt < 2; ++nt) {
            accR[nt] = (f32x4){0.f, 0.f, 0.f, 0.f};
            accZ[nt] = (f32x4){0.f, 0.f, 0.f, 0.f};
            accXN[nt] = (f32x4){0.f, 0.f, 0.f, 0.f};
            accHN[nt] = (f32x4){0.f, 0.f, 0.f, 0.f};
#pragma unroll
            for (int kt = 0; kt < 6; ++kt) {
                accR[nt] = __builtin_amdgcn_mfma_f32_16x16x32_bf16(A[kt], Br[nt][kt], accR[nt], 0, 0, 0);
                accZ[nt] = __builtin_amdgcn_mfma_f32_16x16x32_bf16(A[kt], Bz[nt][kt], accZ[nt], 0, 0, 0);
            }
#pragma unroll
            for (int kt = 0; kt < 2; ++kt)
                accXN[nt] = __builtin_amdgcn_mfma_f32_16x16x32_bf16(A[kt], Bxn[nt][kt], accXN[nt], 0, 0, 0);
#pragma unroll
            for (int kt = 0; kt < 4; ++kt)
                accHN[nt] = __builtin_amdgcn_mfma_f32_16x16x32_bf16(A[kt + 2], Bhn[nt][kt], accHN[nt], 0, 0, 0);
        }
        // C layout: col=lane&15, row=q*4+r
#pragma unroll
        for (int nt = 0; nt < 2; ++nt) {
            const int colbase = wv * 32 + nt * 16 + c;
#pragma unroll
            for (int r = 0; r < 4; ++r) {
                const int m = q * 4 + r;
                gates[m][colbase]       = accR[nt][r];
                gates[m][128 + colbase] = accZ[nt][r];
                gates[m][256 + colbase] = accXN[nt][r];
                gates[m][384 + colbase] = accHN[nt][r];
            }
        }
        __syncthreads();

        // (e) gate nonlinearities + h update (fp32 state)
#pragma unroll
        for (int bi = 0; bi < 8; ++bi) {
            const int b = bg * 8 + bi;
            const float r  = sigmoidf_fast(gates[b][ei] + bR);
            const float z  = sigmoidf_fast(gates[b][128 + ei] + bZ);
            const float xn = gates[b][256 + ei] + bXN;
            const float hn = gates[b][384 + ei] + bHN;
            const float n  = tanhf_fast(xn + r * hn);
            const float h  = (1.0f - z) * n + z * h_f[b][ei];
            h_f[b][ei] = h;
            xt_h[b][64 + ei] = bf16_of(h);
        }
        __syncthreads();

        // (g) readout x_hat = h_new @ W_out^T + b_out (waves 0,1)
        if (wv < 2) {
            bf16x8 Ah[4];
#pragma unroll
            for (int kt = 0; kt < 4; ++kt)
                Ah[kt] = *(const bf16x8*)&xt_h[c][64 + kt * 32 + q * 8];
            f32x4 acc = (f32x4){0.f, 0.f, 0.f, 0.f};
#pragma unroll
            for (int kt = 0; kt < 4; ++kt)
                acc = __builtin_amdgcn_mfma_f32_16x16x32_bf16(Ah[kt], Bo[kt], acc, 0, 0, 0);
            const int col = wv * 16 + c;
#pragma unroll
            for (int r = 0; r < 4; ++r) {
                const int m = q * 4 + r;
                const float v = acc[r] + bo;
                xh[m][col] = v;
                out[((size_t)(bb + m) * TT + (t + 1)) * D_IN + col] = v;
            }
        }
        __syncthreads();
    }
}

extern "C" void kernel_launch(void* const* d_in, const int* in_sizes, int n_in,
                              void* d_out, int out_size, void* d_ws, size_t ws_size,
                              hipStream_t stream) {
    const float* x     = (const float*)d_in[0];
    const float* W_ih  = (const float*)d_in[1];
    const float* W_hh  = (const float*)d_in[2];
    const float* b_ih  = (const float*)d_in[3];
    const float* b_hh  = (const float*)d_in[4];
    const float* W_out = (const float*)d_in[5];
    const float* b_out = (const float*)d_in[6];
    const int*   mask  = (const int*)d_in[7];
    float* out = (float*)d_out;

    rnn_imputer<<<dim3(BATCH / GB), dim3(256), 0, stream>>>(
        x, W_ih, W_hh, b_ih, b_hh, W_out, b_out, mask, out);
}